// Round 6
// baseline (563.742 us; speedup 1.0000x reference)
//
#include <hip/hip_runtime.h>
#include <hip/hip_bf16.h>
#include <math.h>

#define NL 30
#define NM 80
#define Bx 8
#define Tx 8192

typedef short short8 __attribute__((ext_vector_type(8)));
typedef float f32x4 __attribute__((ext_vector_type(4)));
typedef unsigned int u32x2 __attribute__((ext_vector_type(2)));
typedef unsigned int u32x4 __attribute__((ext_vector_type(4)));

__device__ __forceinline__ float bf2f(unsigned short u) {
    union { unsigned int u; float f; } v; v.u = ((unsigned int)u) << 16; return v.f;
}
__device__ __forceinline__ unsigned short f2bf(float f) {
    union { float f; unsigned int u; } v; v.f = f;
    unsigned int r = v.u + 0x7FFFu + ((v.u >> 16) & 1u);
    return (unsigned short)(r >> 16);
}

#if defined(__has_builtin)
#if __has_builtin(__builtin_amdgcn_global_load_lds)
#define HAS_GLL 1
#endif
#endif

__device__ __forceinline__ void gll16(const void* g, void* l) {
#ifdef HAS_GLL
    __builtin_amdgcn_global_load_lds(
        (const __attribute__((address_space(1))) void*)g,
        (__attribute__((address_space(3))) void*)l, 16, 0, 0);
#else
    int lane = threadIdx.x & 63;
    *(u32x4*)((char*)l + lane * 16) = *(const u32x4*)((const char*)g + lane * 16);
#endif
}

// ---------------- merged setup: te (blocks 0-7) | prep (8-1945) | in_conv (1946-2201) ----------------
__global__ __launch_bounds__(512) void setup_kernel(
        const int* __restrict__ tin,
        const float* __restrict__ w1, const float* __restrict__ b1,
        const float* __restrict__ w2, const float* __restrict__ b2,
        float* __restrict__ te_out,
        const float* __restrict__ dconv_w, const float* __restrict__ rs_w,
        const float* __restrict__ skip_w, const float* __restrict__ out_w,
        unsigned short* __restrict__ wc2, unsigned short* __restrict__ wr2,
        unsigned short* __restrict__ skw16, unsigned short* __restrict__ oww16,
        const float* __restrict__ x, const float* __restrict__ in_w,
        const float* __restrict__ in_b, unsigned short* __restrict__ h0) {
    __shared__ float smem[5120];   // te: 1152 floats; in_conv: 5120 floats
    int blk = blockIdx.x;
    int tid = threadIdx.x;
    if (blk < 8) {
        // ---- time-embedding MLP, one block per batch ----
        float* emb = smem;          // 128
        float* h1s = smem + 128;    // 512
        float* red = smem + 640;    // 512
        int b = blk;
        if (tid < 64) {
            float fr = expf(-(float)tid * (logf(10000.f) / 63.f));
            float ang = (float)tin[b] * fr;
            emb[tid] = sinf(ang);
            emb[tid + 64] = cosf(ang);
        }
        __syncthreads();
        float a = b1[tid];
        const float* wr = w1 + tid * 128;
        for (int k = 0; k < 128; ++k) a = fmaf(emb[k], wr[k], a);
        float sp = (a > 15.f) ? a : log1pf(expf(a));
        h1s[tid] = a * tanhf(sp);
        __syncthreads();
        int o = tid & 127, q = tid >> 7;
        float p = 0.f;
        const float* wr2 = w2 + o * 512 + q * 128;
        const float* hq = h1s + q * 128;
        for (int k = 0; k < 128; ++k) p = fmaf(hq[k], wr2[k], p);
        red[tid] = p;
        __syncthreads();
        if (q == 0)
            te_out[b * 128 + o] = b2[o] + red[o] + red[o + 128] + red[o + 256] + red[o + 384];
    } else if (blk < 1946) {
        // ---- weight prep: pre-swizzled wc2/wr2 + bf16 skw/oww ----
        int idx = (blk - 8) * 512 + tid;
        const int totC = NL * 24576;           // 737280
        const int totR = NL * 128 * 64;        // 245760
        if (idx < totC) {
            int l = idx / 24576;
            int r = idx - l * 24576;
            int c = r >> 3;
            int e = r & 7;
            int row = c >> 3;
            int p = c & 7;
            int col16 = p ^ (row & 7);
            int ic = col16 * 8 + e;
            int tap = row >> 7;
            int oc = row & 127;
            wc2[idx] = f2bf(dconv_w[((size_t)(l * 128 + oc) * 64 + ic) * 3 + tap]);
        } else if (idx < totC + totR) {
            int j = idx - totC;
            int l = j / 8192;
            int r = j - l * 8192;
            int c = r >> 3;
            int e = r & 7;
            int row = c >> 3;
            int p = c & 7;
            int col16 = p ^ (row & 7);
            int ic = col16 * 8 + e;
            wr2[j] = f2bf(rs_w[(size_t)(l * 128 + row) * 64 + ic]);
        } else if (idx < totC + totR + 4096) {
            int j = idx - totC - totR;
            skw16[j] = f2bf(skip_w[j] * 0.18257418583505536f);
        } else if (idx < totC + totR + 4096 + 5120) {
            int j = idx - totC - totR - 4096;
            oww16[j] = f2bf(out_w[j]);
        }
    } else {
        // ---- input conv 80->64 + transpose to (B,T,64) bf16; 256 pos/block ----
        float (*wT)[64] = (float(*)[64])smem;
        for (int i = tid; i < NM * 64; i += 512) {
            int m = i >> 6, c = i & 63;
            wT[m][c] = in_w[c * NM + m];
        }
        __syncthreads();
        int j = blk - 1946;
        int b = j >> 5;
        int t = (j & 31) * 256 + (tid >> 1);
        int ch0 = (tid & 1) * 32;
        const float* xp = x + (size_t)b * NM * Tx + t;
        float acc[32];
        #pragma unroll
        for (int c = 0; c < 32; ++c) acc[c] = in_b[ch0 + c];
        for (int m = 0; m < NM; ++m) {
            float xv = xp[(size_t)m * Tx];
            #pragma unroll
            for (int c = 0; c < 32; ++c) acc[c] = fmaf(xv, wT[m][ch0 + c], acc[c]);
        }
        unsigned short* hp = h0 + ((size_t)b * Tx + t) * 64 + ch0;
        #pragma unroll
        for (int c = 0; c < 32; c += 2) {
            unsigned int p = (unsigned int)f2bf(acc[c]) | ((unsigned int)f2bf(acc[c + 1]) << 16);
            *(unsigned int*)(hp + c) = p;
        }
    }
}

// ---------------- per-layer (b,ch) bias: coalesced wave-reduce ----------------
__global__ void gbias_kernel(const float* __restrict__ te,
                             const float* __restrict__ cemb,
                             const float* __restrict__ tpw, const float* __restrict__ tpb,
                             const float* __restrict__ cpw, const float* __restrict__ cpb,
                             const float* __restrict__ dcb,
                             float* __restrict__ gbias) {
    int l = blockIdx.x >> 3;
    int b = blockIdx.x & 7;
    int tid = threadIdx.x, wid = tid >> 6, lane = tid & 63;
    float te0 = te[b * 128 + lane];
    float te1 = te[b * 128 + 64 + lane];
    float ce0 = cemb[b * 256 + lane];
    float ce1 = cemb[b * 256 + 64 + lane];
    float ce2 = cemb[b * 256 + 128 + lane];
    float ce3 = cemb[b * 256 + 192 + lane];
    #pragma unroll 4
    for (int i = 0; i < 16; ++i) {
        int ch = i * 8 + wid;
        const float* wr = tpw + (size_t)(l * 128 + ch) * 128;
        float s = te0 * wr[lane] + te1 * wr[lane + 64];
        const float* wc = cpw + (size_t)(l * 128 + ch) * 256;
        float sc = ce0 * wc[lane] + ce1 * wc[lane + 64] + ce2 * wc[lane + 128] + ce3 * wc[lane + 192];
        #pragma unroll
        for (int off = 32; off >= 1; off >>= 1) {
            s += __shfl_xor(s, off, 64);
            sc += __shfl_xor(sc, off, 64);
        }
        if (lane == 0) {
            float tp = tpb[l * 128 + ch] + s;
            float cp = cpb[l * 128 + ch] + sc;
            float s1 = tp / fmaxf(fabsf(tp), 1e-12f);
            float s2 = cp / fmaxf(fabsf(cp), 1e-12f);
            gbias[(l * 8 + b) * 128 + ch] = dcb[l * 128 + ch] + s1 + s2;
        }
    }
}

// ---------------- fused residual layer (layers 0..28) ----------------
// 8 waves; wave = M128 out-ch x N16 positions. Grid 512 = 2 blocks/CU.
// h_old*sqrt(2) and skips_old folded into rs accumulator init.
__launch_bounds__(512, 4)
__global__ void layer_kernel(const unsigned short* __restrict__ h_in,
                             unsigned short* __restrict__ h_out,
                             float* __restrict__ skips,
                             const unsigned short* __restrict__ wc2,  // pre-swizzled
                             const unsigned short* __restrict__ wr2,  // pre-swizzled
                             const float* __restrict__ gbias,         // [8][128]
                             const float* __restrict__ rsb,           // [128]
                             int dil, int first) {
    __shared__ __align__(16) unsigned char lds[81920];
    unsigned char* ldsA = lds;            // 48KB conv weights
    unsigned char* ldsR = lds + 49152;    // 16KB rs weights
    unsigned char* ldsO = lds + 65536;    // 16KB out exchange (2KB/wave)

    int tid = threadIdx.x;
    int wid = tid >> 6, lane = tid & 63, lr = lane & 15, lq = lane >> 4;

    #pragma unroll
    for (int j = 0; j < 6; ++j) {
        int cbase = j * 512 + wid * 64;
        gll16(wc2 + (size_t)(cbase + lane) * 8, ldsA + cbase * 16);
    }
    #pragma unroll
    for (int j = 0; j < 2; ++j) {
        int cbase = j * 512 + wid * 64;
        gll16(wr2 + (size_t)(cbase + lane) * 8, ldsR + cbase * 16);
    }

    int bid = blockIdx.x;
    int wg = (bid & 7) * 64 + (bid >> 3);   // batch k -> XCD k
    int b = wg >> 6;
    int t0 = ((wg & 63) << 7) + wid * 16;

    const unsigned short* hb = h_in + (size_t)b * Tx * 64;
    short8 bv[3][2];
    #pragma unroll
    for (int tap = 0; tap < 3; ++tap) {
        int toff = (tap - 1) * dil;
        int t = t0 + lr + toff;
        bool v = ((unsigned)t < (unsigned)Tx);
        #pragma unroll
        for (int kc = 0; kc < 2; ++kc) {
            short8 z = {0, 0, 0, 0, 0, 0, 0, 0};
            if (v) z = *(const short8*)(hb + t * 64 + kc * 32 + lq * 8);
            bv[tap][kc] = z;
        }
    }

    f32x4 acc[8];
    #pragma unroll
    for (int mf = 0; mf < 8; ++mf)
        acc[mf] = *(const f32x4*)(gbias + b * 128 + mf * 16 + lq * 4);
    __syncthreads();   // weights staged

    #pragma unroll
    for (int tap = 0; tap < 3; ++tap) {
        #pragma unroll
        for (int kc = 0; kc < 2; ++kc) {
            #pragma unroll
            for (int mf = 0; mf < 8; ++mf) {
                int row = tap * 128 + mf * 16 + lr;
                short8 af = *(const short8*)(ldsA + row * 128 + ((kc * 64 + lq * 16) ^ ((lr & 7) << 4)));
                acc[mf] = __builtin_amdgcn_mfma_f32_16x16x32_bf16(af, bv[tap][kc], acc[mf], 0, 0, 0);
            }
        }
    }

    // issue epilogue loads early (consumed at racc init, hidden under gating)
    size_t base = ((size_t)b * Tx + t0 + lr) * 64;
    u32x2 hv[4];
    f32x4 sko[4];
    #pragma unroll
    for (int mf = 0; mf < 4; ++mf) {
        hv[mf] = *(const u32x2*)(h_in + base + mf * 16 + lq * 4);
        if (!first) sko[mf] = *(const f32x4*)(skips + base + mf * 16 + lq * 4);
        else { sko[mf][0] = 0.f; sko[mf][1] = 0.f; sko[mf][2] = 0.f; sko[mf][3] = 0.f; }
    }

    // gating -> wave-private ldsO tile (16 pos x 64 ch)
    unsigned char* myO = ldsO + wid * 2048;
    #pragma unroll
    for (int mf = 0; mf < 4; ++mf) {
        int p = lr;
        unsigned short ob[4];
        #pragma unroll
        for (int r = 0; r < 4; ++r) {
            float g = acc[mf][r];
            float f = acc[mf + 4][r];
            f = fminf(f, 15.f);
            g = fminf(g, 30.f);
            float ea = __builtin_amdgcn_exp2f(f * 2.8853900817779268f);
            float eb = __builtin_amdgcn_exp2f(g * 1.4426950408889634f);
            float num = (ea - 1.f) * eb;
            float den = (ea + 1.f) * (1.f + eb);
            ob[r] = f2bf(num * __builtin_amdgcn_rcpf(den));
        }
        u32x2 pk;
        pk[0] = (unsigned int)ob[0] | ((unsigned int)ob[1] << 16);
        pk[1] = (unsigned int)ob[2] | ((unsigned int)ob[3] << 16);
        *(u32x2*)(myO + p * 128 + ((mf * 32 + lq * 8) ^ ((p & 7) << 4))) = pk;
    }

    // rs accumulators: res half folds h_old*sqrt(2); skip half folds skips_old
    const float rt2 = 1.41421356237309505f;
    f32x4 racc[8];
    #pragma unroll
    for (int mf = 0; mf < 4; ++mf) {
        f32x4 rb = *(const f32x4*)(rsb + mf * 16 + lq * 4);
        unsigned short* hp = (unsigned short*)&hv[mf];
        f32x4 r;
        #pragma unroll
        for (int r_ = 0; r_ < 4; ++r_) r[r_] = fmaf(bf2f(hp[r_]), rt2, rb[r_]);
        racc[mf] = r;
    }
    #pragma unroll
    for (int mf = 0; mf < 4; ++mf)
        racc[mf + 4] = *(const f32x4*)(rsb + 64 + mf * 16 + lq * 4) + sko[mf];

    #pragma unroll
    for (int kc = 0; kc < 2; ++kc) {
        int p = lr;
        short8 ov = *(const short8*)(myO + p * 128 + ((kc * 64 + lq * 16) ^ ((p & 7) << 4)));
        #pragma unroll
        for (int mf = 0; mf < 8; ++mf) {
            int row = mf * 16 + lr;
            short8 af = *(const short8*)(ldsR + row * 128 + ((kc * 64 + lq * 16) ^ ((lr & 7) << 4)));
            racc[mf] = __builtin_amdgcn_mfma_f32_16x16x32_bf16(af, ov, racc[mf], 0, 0, 0);
        }
    }

    // epilogue: h_out = racc*inv_s2 (bf16); skips = racc[4..7] (f32)
    const float inv_s2 = 0.70710678118654752f;
    #pragma unroll
    for (int mf = 0; mf < 4; ++mf) {
        unsigned short hnew[4];
        #pragma unroll
        for (int r = 0; r < 4; ++r)
            hnew[r] = f2bf(racc[mf][r] * inv_s2);
        u32x2 hw;
        hw[0] = (unsigned int)hnew[0] | ((unsigned int)hnew[1] << 16);
        hw[1] = (unsigned int)hnew[2] | ((unsigned int)hnew[3] << 16);
        *(u32x2*)(h_out + base + mf * 16 + lq * 4) = hw;
        *(f32x4*)(skips + base + mf * 16 + lq * 4) = racc[mf + 4];
    }
}

// ---------------- last layer (29) + fused skip_conv -> relu -> out_conv ----------------
// Same conv+gating as layer_kernel; rs computes only the skip half; skip tile goes
// through the wave-private swizzled LDS exchange into the two 1x1 output convs.
__launch_bounds__(512, 2)
__global__ void layer_last_kernel(const unsigned short* __restrict__ h_in,
                                  const float* __restrict__ skips,
                                  const unsigned short* __restrict__ wc2,
                                  const unsigned short* __restrict__ wr2,
                                  const float* __restrict__ gbias,
                                  const float* __restrict__ rsb,
                                  const unsigned short* __restrict__ skw,  // [64][64] bf16 (isc folded)
                                  const float* __restrict__ skb,
                                  const unsigned short* __restrict__ oww,  // [80][64] bf16
                                  const float* __restrict__ obias,
                                  float* __restrict__ y,
                                  int dil) {
    __shared__ __align__(16) unsigned char lds[81920];
    unsigned char* ldsA = lds;
    unsigned char* ldsR = lds + 49152;
    unsigned char* ldsO = lds + 65536;

    int tid = threadIdx.x;
    int wid = tid >> 6, lane = tid & 63, lr = lane & 15, lq = lane >> 4;

    #pragma unroll
    for (int j = 0; j < 6; ++j) {
        int cbase = j * 512 + wid * 64;
        gll16(wc2 + (size_t)(cbase + lane) * 8, ldsA + cbase * 16);
    }
    #pragma unroll
    for (int j = 0; j < 2; ++j) {
        int cbase = j * 512 + wid * 64;
        gll16(wr2 + (size_t)(cbase + lane) * 8, ldsR + cbase * 16);
    }

    int bid = blockIdx.x;
    int wg = (bid & 7) * 64 + (bid >> 3);
    int b = wg >> 6;
    int t0 = ((wg & 63) << 7) + wid * 16;

    const unsigned short* hb = h_in + (size_t)b * Tx * 64;
    short8 bv[3][2];
    #pragma unroll
    for (int tap = 0; tap < 3; ++tap) {
        int toff = (tap - 1) * dil;
        int t = t0 + lr + toff;
        bool v = ((unsigned)t < (unsigned)Tx);
        #pragma unroll
        for (int kc = 0; kc < 2; ++kc) {
            short8 z = {0, 0, 0, 0, 0, 0, 0, 0};
            if (v) z = *(const short8*)(hb + t * 64 + kc * 32 + lq * 8);
            bv[tap][kc] = z;
        }
    }

    f32x4 acc[8];
    #pragma unroll
    for (int mf = 0; mf < 8; ++mf)
        acc[mf] = *(const f32x4*)(gbias + b * 128 + mf * 16 + lq * 4);
    __syncthreads();

    #pragma unroll
    for (int tap = 0; tap < 3; ++tap) {
        #pragma unroll
        for (int kc = 0; kc < 2; ++kc) {
            #pragma unroll
            for (int mf = 0; mf < 8; ++mf) {
                int row = tap * 128 + mf * 16 + lr;
                short8 af = *(const short8*)(ldsA + row * 128 + ((kc * 64 + lq * 16) ^ ((lr & 7) << 4)));
                acc[mf] = __builtin_amdgcn_mfma_f32_16x16x32_bf16(af, bv[tap][kc], acc[mf], 0, 0, 0);
            }
        }
    }

    // skips_old load (early)
    size_t base = ((size_t)b * Tx + t0 + lr) * 64;
    f32x4 sko[4];
    #pragma unroll
    for (int mf = 0; mf < 4; ++mf)
        sko[mf] = *(const f32x4*)(skips + base + mf * 16 + lq * 4);

    // gating -> wave-private ldsO
    unsigned char* myO = ldsO + wid * 2048;
    #pragma unroll
    for (int mf = 0; mf < 4; ++mf) {
        int p = lr;
        unsigned short ob[4];
        #pragma unroll
        for (int r = 0; r < 4; ++r) {
            float g = acc[mf][r];
            float f = acc[mf + 4][r];
            f = fminf(f, 15.f);
            g = fminf(g, 30.f);
            float ea = __builtin_amdgcn_exp2f(f * 2.8853900817779268f);
            float eb = __builtin_amdgcn_exp2f(g * 1.4426950408889634f);
            float num = (ea - 1.f) * eb;
            float den = (ea + 1.f) * (1.f + eb);
            ob[r] = f2bf(num * __builtin_amdgcn_rcpf(den));
        }
        u32x2 pk;
        pk[0] = (unsigned int)ob[0] | ((unsigned int)ob[1] << 16);
        pk[1] = (unsigned int)ob[2] | ((unsigned int)ob[3] << 16);
        *(u32x2*)(myO + p * 128 + ((mf * 32 + lq * 8) ^ ((p & 7) << 4))) = pk;
    }

    // rs: skip half only (och 64..127)
    f32x4 racc[4];
    #pragma unroll
    for (int mf = 0; mf < 4; ++mf)
        racc[mf] = *(const f32x4*)(rsb + 64 + mf * 16 + lq * 4) + sko[mf];
    #pragma unroll
    for (int kc = 0; kc < 2; ++kc) {
        int p = lr;
        short8 ov = *(const short8*)(myO + p * 128 + ((kc * 64 + lq * 16) ^ ((p & 7) << 4)));
        #pragma unroll
        for (int mf = 0; mf < 4; ++mf) {
            int row = 64 + mf * 16 + lr;
            short8 af = *(const short8*)(ldsR + row * 128 + ((kc * 64 + lq * 16) ^ ((lr & 7) << 4)));
            racc[mf] = __builtin_amdgcn_mfma_f32_16x16x32_bf16(af, ov, racc[mf], 0, 0, 0);
        }
    }

    // skip tile -> bf16 -> myO (isc is folded into skw)
    #pragma unroll
    for (int mf = 0; mf < 4; ++mf) {
        int p = lr;
        u32x2 pk;
        pk[0] = (unsigned int)f2bf(racc[mf][0]) | ((unsigned int)f2bf(racc[mf][1]) << 16);
        pk[1] = (unsigned int)f2bf(racc[mf][2]) | ((unsigned int)f2bf(racc[mf][3]) << 16);
        *(u32x2*)(myO + p * 128 + ((mf * 32 + lq * 8) ^ ((p & 7) << 4))) = pk;
    }

    // skip_conv (64->64) + relu
    f32x4 yacc[4];
    #pragma unroll
    for (int mf = 0; mf < 4; ++mf)
        yacc[mf] = *(const f32x4*)(skb + mf * 16 + lq * 4);
    #pragma unroll
    for (int kc = 0; kc < 2; ++kc) {
        int p = lr;
        short8 Bv = *(const short8*)(myO + p * 128 + ((kc * 64 + lq * 16) ^ ((p & 7) << 4)));
        #pragma unroll
        for (int mf = 0; mf < 4; ++mf) {
            short8 A1 = *(const short8*)(skw + (mf * 16 + lr) * 64 + kc * 32 + lq * 8);
            yacc[mf] = __builtin_amdgcn_mfma_f32_16x16x32_bf16(A1, Bv, yacc[mf], 0, 0, 0);
        }
    }
    #pragma unroll
    for (int mf = 0; mf < 4; ++mf) {
        int p = lr;
        u32x2 pk;
        pk[0] = (unsigned int)f2bf(fmaxf(yacc[mf][0], 0.f)) | ((unsigned int)f2bf(fmaxf(yacc[mf][1], 0.f)) << 16);
        pk[1] = (unsigned int)f2bf(fmaxf(yacc[mf][2], 0.f)) | ((unsigned int)f2bf(fmaxf(yacc[mf][3], 0.f)) << 16);
        *(u32x2*)(myO + p * 128 + ((mf * 32 + lq * 8) ^ ((p & 7) << 4))) = pk;
    }

    // out_conv (64->80), store y f32
    f32x4 oacc[5];
    #pragma unroll
    for (int mf = 0; mf < 5; ++mf)
        oacc[mf] = *(const f32x4*)(obias + mf * 16 + lq * 4);
    #pragma unroll
    for (int kc = 0; kc < 2; ++kc) {
        int p = lr;
        short8 B2 = *(const short8*)(myO + p * 128 + ((kc * 64 + lq * 16) ^ ((p & 7) << 4)));
        #pragma unroll
        for (int mf = 0; mf < 5; ++mf) {
            short8 A2 = *(const short8*)(oww + (mf * 16 + lr) * 64 + kc * 32 + lq * 8);
            oacc[mf] = __builtin_amdgcn_mfma_f32_16x16x32_bf16(A2, B2, oacc[mf], 0, 0, 0);
        }
    }
    int t = t0 + lr;
    #pragma unroll
    for (int mf = 0; mf < 5; ++mf) {
        #pragma unroll
        for (int r = 0; r < 4; ++r) {
            int m = mf * 16 + lq * 4 + r;
            y[((size_t)b * NM + m) * Tx + t] = oacc[mf][r];
        }
    }
}

extern "C" void kernel_launch(void* const* d_in, const int* in_sizes, int n_in,
                              void* d_out, int out_size, void* d_ws, size_t ws_size,
                              hipStream_t stream) {
    const float* x       = (const float*)d_in[0];
    const int*   tin     = (const int*)d_in[1];
    const float* c_emb   = (const float*)d_in[2];
    const float* in_w    = (const float*)d_in[3];
    const float* in_b    = (const float*)d_in[4];
    const float* te_w1   = (const float*)d_in[5];
    const float* te_b1   = (const float*)d_in[6];
    const float* te_w2   = (const float*)d_in[7];
    const float* te_b2   = (const float*)d_in[8];
    const float* dconv_w = (const float*)d_in[9];
    const float* dconv_b = (const float*)d_in[10];
    const float* tproj_w = (const float*)d_in[11];
    const float* tproj_b = (const float*)d_in[12];
    const float* cproj_w = (const float*)d_in[13];
    const float* cproj_b = (const float*)d_in[14];
    const float* rs_w    = (const float*)d_in[15];
    const float* rs_b    = (const float*)d_in[16];
    const float* skip_w  = (const float*)d_in[17];
    const float* skip_b  = (const float*)d_in[18];
    const float* out_w   = (const float*)d_in[19];
    const float* out_b   = (const float*)d_in[20];

    char* ws = (char*)d_ws;
    float* te_buf         = (float*)(ws + 0);                 // 4KB
    float* gbias          = (float*)(ws + 4096);              // 120KB -> 126976
    unsigned short* skw16 = (unsigned short*)(ws + 126976);   // 8KB  -> 135168
    unsigned short* oww16 = (unsigned short*)(ws + 135168);   // 10KB -> 145408
    unsigned short* wc2   = (unsigned short*)(ws + 145408);   // 1.40625MB -> 1619968
    unsigned short* wr2   = (unsigned short*)(ws + 1619968);  // 480KB -> 2111488
    unsigned short* h0    = (unsigned short*)(ws + 2111488);  // 8MB -> 10500096
    unsigned short* h1    = (unsigned short*)(ws + 10500096); // 8MB -> 18888704
    float* skips          = (float*)(ws + 18888704);          // 16MB -> 35665920

    setup_kernel<<<2202, 512, 0, stream>>>(tin, te_w1, te_b1, te_w2, te_b2, te_buf,
                                           dconv_w, rs_w, skip_w, out_w,
                                           wc2, wr2, skw16, oww16,
                                           x, in_w, in_b, h0);
    gbias_kernel<<<240, 512, 0, stream>>>(te_buf, c_emb, tproj_w, tproj_b,
                                          cproj_w, cproj_b, dconv_b, gbias);

    unsigned short* hin = h0;
    unsigned short* hout = h1;
    for (int i = 0; i < NL - 1; ++i) {
        int dil = 1 << (i % 10);
        layer_kernel<<<512, 512, 0, stream>>>(hin, hout, skips,
                                              wc2 + (size_t)i * 24576,
                                              wr2 + (size_t)i * 8192,
                                              gbias + (size_t)i * 1024,
                                              rs_b + (size_t)i * 128,
                                              dil, i == 0 ? 1 : 0);
        unsigned short* tmp = hin; hin = hout; hout = tmp;
    }
    layer_last_kernel<<<512, 512, 0, stream>>>(hin, skips,
                                               wc2 + (size_t)(NL - 1) * 24576,
                                               wr2 + (size_t)(NL - 1) * 8192,
                                               gbias + (size_t)(NL - 1) * 1024,
                                               rs_b + (size_t)(NL - 1) * 128,
                                               skw16, skip_b, oww16, out_b,
                                               (float*)d_out, 1 << ((NL - 1) % 10));
}

// Round 7
// 556.031 us; speedup vs baseline: 1.0139x; 1.0139x over previous
//
#include <hip/hip_runtime.h>
#include <hip/hip_bf16.h>
#include <math.h>

#define NL 30
#define NM 80
#define Bx 8
#define Tx 8192

typedef short short8 __attribute__((ext_vector_type(8)));
typedef float f32x4 __attribute__((ext_vector_type(4)));
typedef unsigned int u32x2 __attribute__((ext_vector_type(2)));
typedef unsigned int u32x4 __attribute__((ext_vector_type(4)));

__device__ __forceinline__ float bf2f(unsigned short u) {
    union { unsigned int u; float f; } v; v.u = ((unsigned int)u) << 16; return v.f;
}
__device__ __forceinline__ unsigned short f2bf(float f) {
    union { float f; unsigned int u; } v; v.f = f;
    unsigned int r = v.u + 0x7FFFu + ((v.u >> 16) & 1u);
    return (unsigned short)(r >> 16);
}

#if defined(__has_builtin)
#if __has_builtin(__builtin_amdgcn_global_load_lds)
#define HAS_GLL 1
#endif
#endif

__device__ __forceinline__ void gll16(const void* g, void* l) {
#ifdef HAS_GLL
    __builtin_amdgcn_global_load_lds(
        (const __attribute__((address_space(1))) void*)g,
        (__attribute__((address_space(3))) void*)l, 16, 0, 0);
#else
    int lane = threadIdx.x & 63;
    *(u32x4*)((char*)l + lane * 16) = *(const u32x4*)((const char*)g + lane * 16);
#endif
}

// ---------------- merged setup ----------------
// blocks 0-7: te | 8-37: wc2 transpose (1/layer) | 38-67: wr2 transpose (1/layer)
// | 68: skw/oww | 69-324: in_conv (256 pos/block)
__global__ __launch_bounds__(512) void setup_kernel(
        const int* __restrict__ tin,
        const float* __restrict__ w1, const float* __restrict__ b1,
        const float* __restrict__ w2, const float* __restrict__ b2,
        float* __restrict__ te_out,
        const float* __restrict__ dconv_w, const float* __restrict__ rs_w,
        const float* __restrict__ skip_w, const float* __restrict__ out_w,
        unsigned short* __restrict__ wc2, unsigned short* __restrict__ wr2,
        unsigned short* __restrict__ skw16, unsigned short* __restrict__ oww16,
        const float* __restrict__ x, const float* __restrict__ in_w,
        const float* __restrict__ in_b, unsigned short* __restrict__ h0) {
    __shared__ __align__(16) unsigned char smem[49152];
    int blk = blockIdx.x;
    int tid = threadIdx.x;
    if (blk < 8) {
        // ---- time-embedding MLP, one block per batch ----
        float* emb = (float*)smem;          // 128
        float* h1s = (float*)smem + 128;    // 512
        float* red = (float*)smem + 640;    // 512
        int b = blk;
        if (tid < 64) {
            float fr = expf(-(float)tid * (logf(10000.f) / 63.f));
            float ang = (float)tin[b] * fr;
            emb[tid] = sinf(ang);
            emb[tid + 64] = cosf(ang);
        }
        __syncthreads();
        float a = b1[tid];
        const float* wr = w1 + tid * 128;
        for (int k = 0; k < 128; ++k) a = fmaf(emb[k], wr[k], a);
        float sp = (a > 15.f) ? a : log1pf(expf(a));
        h1s[tid] = a * tanhf(sp);
        __syncthreads();
        int o = tid & 127, q = tid >> 7;
        float p = 0.f;
        const float* wr2_ = w2 + o * 512 + q * 128;
        const float* hq = h1s + q * 128;
        for (int k = 0; k < 128; ++k) p = fmaf(hq[k], wr2_[k], p);
        red[tid] = p;
        __syncthreads();
        if (q == 0)
            te_out[b * 128 + o] = b2[o] + red[o] + red[o + 128] + red[o + 256] + red[o + 384];
    } else if (blk < 38) {
        // ---- wc2: coalesced read -> LDS swizzle-stage -> coalesced write ----
        int l = blk - 8;
        unsigned short* st = (unsigned short*)smem;   // 24576 bf16 = 48KB
        const float* src = dconv_w + (size_t)l * 24576;
        #pragma unroll 1
        for (int it = 0; it < 48; ++it) {
            int sidx = it * 512 + tid;
            float v = src[sidx];
            int oc = sidx / 192;
            int r = sidx - oc * 192;
            int ic = r / 3;
            int tap = r - ic * 3;
            int dst = tap * 8192 + oc * 64 + (((ic >> 3) ^ (oc & 7)) << 3) + (ic & 7);
            st[dst] = f2bf(v);
        }
        __syncthreads();
        u32x4* dst4 = (u32x4*)(wc2 + (size_t)l * 24576);
        const u32x4* src4 = (const u32x4*)st;
        #pragma unroll
        for (int it = 0; it < 6; ++it)
            dst4[it * 512 + tid] = src4[it * 512 + tid];
    } else if (blk < 68) {
        // ---- wr2: same treatment ----
        int l = blk - 38;
        unsigned short* st = (unsigned short*)smem;   // 8192 bf16 = 16KB
        const float* src = rs_w + (size_t)l * 8192;
        #pragma unroll
        for (int it = 0; it < 16; ++it) {
            int sidx = it * 512 + tid;
            float v = src[sidx];
            int row = sidx >> 6;
            int ic = sidx & 63;
            int dst = row * 64 + (((ic >> 3) ^ (row & 7)) << 3) + (ic & 7);
            st[dst] = f2bf(v);
        }
        __syncthreads();
        u32x4* dst4 = (u32x4*)(wr2 + (size_t)l * 8192);
        const u32x4* src4 = (const u32x4*)st;
        #pragma unroll
        for (int it = 0; it < 2; ++it)
            dst4[it * 512 + tid] = src4[it * 512 + tid];
    } else if (blk == 68) {
        // ---- skw16 / oww16 ----
        for (int j = tid; j < 4096; j += 512)
            skw16[j] = f2bf(skip_w[j] * 0.18257418583505536f);
        for (int j = tid; j < 5120; j += 512)
            oww16[j] = f2bf(out_w[j]);
    } else {
        // ---- input conv 80->64 + transpose to (B,T,64) bf16; 256 pos/block ----
        float (*wT)[64] = (float(*)[64])smem;
        for (int i = tid; i < NM * 64; i += 512) {
            int m = i >> 6, c = i & 63;
            wT[m][c] = in_w[c * NM + m];
        }
        __syncthreads();
        int j = blk - 69;
        int b = j >> 5;
        int t = (j & 31) * 256 + (tid >> 1);
        int ch0 = (tid & 1) * 32;
        const float* xp = x + (size_t)b * NM * Tx + t;
        float acc[32];
        #pragma unroll
        for (int c = 0; c < 32; ++c) acc[c] = in_b[ch0 + c];
        #pragma unroll 1
        for (int m0 = 0; m0 < NM; m0 += 8) {
            float xv[8];
            #pragma unroll
            for (int u = 0; u < 8; ++u) xv[u] = xp[(size_t)(m0 + u) * Tx];
            #pragma unroll
            for (int u = 0; u < 8; ++u) {
                #pragma unroll
                for (int c = 0; c < 32; ++c)
                    acc[c] = fmaf(xv[u], wT[m0 + u][ch0 + c], acc[c]);
            }
        }
        unsigned short* hp = h0 + ((size_t)b * Tx + t) * 64 + ch0;
        #pragma unroll
        for (int c = 0; c < 32; c += 2) {
            unsigned int p = (unsigned int)f2bf(acc[c]) | ((unsigned int)f2bf(acc[c + 1]) << 16);
            *(unsigned int*)(hp + c) = p;
        }
    }
}

// ---------------- per-layer (b,ch) bias: coalesced wave-reduce ----------------
__global__ void gbias_kernel(const float* __restrict__ te,
                             const float* __restrict__ cemb,
                             const float* __restrict__ tpw, const float* __restrict__ tpb,
                             const float* __restrict__ cpw, const float* __restrict__ cpb,
                             const float* __restrict__ dcb,
                             float* __restrict__ gbias) {
    int l = blockIdx.x >> 3;
    int b = blockIdx.x & 7;
    int tid = threadIdx.x, wid = tid >> 6, lane = tid & 63;
    float te0 = te[b * 128 + lane];
    float te1 = te[b * 128 + 64 + lane];
    float ce0 = cemb[b * 256 + lane];
    float ce1 = cemb[b * 256 + 64 + lane];
    float ce2 = cemb[b * 256 + 128 + lane];
    float ce3 = cemb[b * 256 + 192 + lane];
    #pragma unroll 4
    for (int i = 0; i < 16; ++i) {
        int ch = i * 8 + wid;
        const float* wr = tpw + (size_t)(l * 128 + ch) * 128;
        float s = te0 * wr[lane] + te1 * wr[lane + 64];
        const float* wc = cpw + (size_t)(l * 128 + ch) * 256;
        float sc = ce0 * wc[lane] + ce1 * wc[lane + 64] + ce2 * wc[lane + 128] + ce3 * wc[lane + 192];
        #pragma unroll
        for (int off = 32; off >= 1; off >>= 1) {
            s += __shfl_xor(s, off, 64);
            sc += __shfl_xor(sc, off, 64);
        }
        if (lane == 0) {
            float tp = tpb[l * 128 + ch] + s;
            float cp = cpb[l * 128 + ch] + sc;
            float s1 = tp / fmaxf(fabsf(tp), 1e-12f);
            float s2 = cp / fmaxf(fabsf(cp), 1e-12f);
            gbias[(l * 8 + b) * 128 + ch] = dcb[l * 128 + ch] + s1 + s2;
        }
    }
}

// ---------------- fused residual layer (layers 0..28) ----------------
// 8 waves; wave = M128 out-ch x N16 positions. Grid 512 = 2 blocks/CU.
// h_old*sqrt(2) and skips_old folded into rs accumulator init.
__launch_bounds__(512, 4)
__global__ void layer_kernel(const unsigned short* __restrict__ h_in,
                             unsigned short* __restrict__ h_out,
                             float* __restrict__ skips,
                             const unsigned short* __restrict__ wc2,  // pre-swizzled
                             const unsigned short* __restrict__ wr2,  // pre-swizzled
                             const float* __restrict__ gbias,         // [8][128]
                             const float* __restrict__ rsb,           // [128]
                             int dil, int first) {
    __shared__ __align__(16) unsigned char lds[81920];
    unsigned char* ldsA = lds;            // 48KB conv weights
    unsigned char* ldsR = lds + 49152;    // 16KB rs weights
    unsigned char* ldsO = lds + 65536;    // 16KB out exchange (2KB/wave)

    int tid = threadIdx.x;
    int wid = tid >> 6, lane = tid & 63, lr = lane & 15, lq = lane >> 4;

    #pragma unroll
    for (int j = 0; j < 6; ++j) {
        int cbase = j * 512 + wid * 64;
        gll16(wc2 + (size_t)(cbase + lane) * 8, ldsA + cbase * 16);
    }
    #pragma unroll
    for (int j = 0; j < 2; ++j) {
        int cbase = j * 512 + wid * 64;
        gll16(wr2 + (size_t)(cbase + lane) * 8, ldsR + cbase * 16);
    }

    int bid = blockIdx.x;
    int wg = (bid & 7) * 64 + (bid >> 3);   // batch k -> XCD k
    int b = wg >> 6;
    int t0 = ((wg & 63) << 7) + wid * 16;

    const unsigned short* hb = h_in + (size_t)b * Tx * 64;
    short8 bv[3][2];
    #pragma unroll
    for (int tap = 0; tap < 3; ++tap) {
        int toff = (tap - 1) * dil;
        int t = t0 + lr + toff;
        bool v = ((unsigned)t < (unsigned)Tx);
        #pragma unroll
        for (int kc = 0; kc < 2; ++kc) {
            short8 z = {0, 0, 0, 0, 0, 0, 0, 0};
            if (v) z = *(const short8*)(hb + t * 64 + kc * 32 + lq * 8);
            bv[tap][kc] = z;
        }
    }

    f32x4 acc[8];
    #pragma unroll
    for (int mf = 0; mf < 8; ++mf)
        acc[mf] = *(const f32x4*)(gbias + b * 128 + mf * 16 + lq * 4);
    __syncthreads();   // weights staged

    #pragma unroll
    for (int tap = 0; tap < 3; ++tap) {
        #pragma unroll
        for (int kc = 0; kc < 2; ++kc) {
            #pragma unroll
            for (int mf = 0; mf < 8; ++mf) {
                int row = tap * 128 + mf * 16 + lr;
                short8 af = *(const short8*)(ldsA + row * 128 + ((kc * 64 + lq * 16) ^ ((lr & 7) << 4)));
                acc[mf] = __builtin_amdgcn_mfma_f32_16x16x32_bf16(af, bv[tap][kc], acc[mf], 0, 0, 0);
            }
        }
    }

    // issue epilogue loads early (consumed at racc init, hidden under gating)
    size_t base = ((size_t)b * Tx + t0 + lr) * 64;
    u32x2 hv[4];
    f32x4 sko[4];
    #pragma unroll
    for (int mf = 0; mf < 4; ++mf) {
        hv[mf] = *(const u32x2*)(h_in + base + mf * 16 + lq * 4);
        if (!first) sko[mf] = *(const f32x4*)(skips + base + mf * 16 + lq * 4);
        else { sko[mf][0] = 0.f; sko[mf][1] = 0.f; sko[mf][2] = 0.f; sko[mf][3] = 0.f; }
    }

    // gating -> wave-private ldsO tile (16 pos x 64 ch)
    unsigned char* myO = ldsO + wid * 2048;
    #pragma unroll
    for (int mf = 0; mf < 4; ++mf) {
        int p = lr;
        unsigned short ob[4];
        #pragma unroll
        for (int r = 0; r < 4; ++r) {
            float g = acc[mf][r];
            float f = acc[mf + 4][r];
            f = fminf(f, 15.f);
            g = fminf(g, 30.f);
            float ea = __builtin_amdgcn_exp2f(f * 2.8853900817779268f);
            float eb = __builtin_amdgcn_exp2f(g * 1.4426950408889634f);
            float num = (ea - 1.f) * eb;
            float den = (ea + 1.f) * (1.f + eb);
            ob[r] = f2bf(num * __builtin_amdgcn_rcpf(den));
        }
        u32x2 pk;
        pk[0] = (unsigned int)ob[0] | ((unsigned int)ob[1] << 16);
        pk[1] = (unsigned int)ob[2] | ((unsigned int)ob[3] << 16);
        *(u32x2*)(myO + p * 128 + ((mf * 32 + lq * 8) ^ ((p & 7) << 4))) = pk;
    }

    // rs accumulators: res half folds h_old*sqrt(2); skip half folds skips_old
    const float rt2 = 1.41421356237309505f;
    f32x4 racc[8];
    #pragma unroll
    for (int mf = 0; mf < 4; ++mf) {
        f32x4 rb = *(const f32x4*)(rsb + mf * 16 + lq * 4);
        unsigned short* hp = (unsigned short*)&hv[mf];
        f32x4 r;
        #pragma unroll
        for (int r_ = 0; r_ < 4; ++r_) r[r_] = fmaf(bf2f(hp[r_]), rt2, rb[r_]);
        racc[mf] = r;
    }
    #pragma unroll
    for (int mf = 0; mf < 4; ++mf)
        racc[mf + 4] = *(const f32x4*)(rsb + 64 + mf * 16 + lq * 4) + sko[mf];

    #pragma unroll
    for (int kc = 0; kc < 2; ++kc) {
        int p = lr;
        short8 ov = *(const short8*)(myO + p * 128 + ((kc * 64 + lq * 16) ^ ((p & 7) << 4)));
        #pragma unroll
        for (int mf = 0; mf < 8; ++mf) {
            int row = mf * 16 + lr;
            short8 af = *(const short8*)(ldsR + row * 128 + ((kc * 64 + lq * 16) ^ ((lr & 7) << 4)));
            racc[mf] = __builtin_amdgcn_mfma_f32_16x16x32_bf16(af, ov, racc[mf], 0, 0, 0);
        }
    }

    // epilogue: h_out = racc*inv_s2 (bf16); skips = racc[4..7] (f32)
    const float inv_s2 = 0.70710678118654752f;
    #pragma unroll
    for (int mf = 0; mf < 4; ++mf) {
        unsigned short hnew[4];
        #pragma unroll
        for (int r = 0; r < 4; ++r)
            hnew[r] = f2bf(racc[mf][r] * inv_s2);
        u32x2 hw;
        hw[0] = (unsigned int)hnew[0] | ((unsigned int)hnew[1] << 16);
        hw[1] = (unsigned int)hnew[2] | ((unsigned int)hnew[3] << 16);
        *(u32x2*)(h_out + base + mf * 16 + lq * 4) = hw;
        *(f32x4*)(skips + base + mf * 16 + lq * 4) = racc[mf + 4];
    }
}

// ---------------- last layer (29) + fused skip_conv -> relu -> out_conv ----------------
__launch_bounds__(512, 2)
__global__ void layer_last_kernel(const unsigned short* __restrict__ h_in,
                                  const float* __restrict__ skips,
                                  const unsigned short* __restrict__ wc2,
                                  const unsigned short* __restrict__ wr2,
                                  const float* __restrict__ gbias,
                                  const float* __restrict__ rsb,
                                  const unsigned short* __restrict__ skw,  // [64][64] bf16 (isc folded)
                                  const float* __restrict__ skb,
                                  const unsigned short* __restrict__ oww,  // [80][64] bf16
                                  const float* __restrict__ obias,
                                  float* __restrict__ y,
                                  int dil) {
    __shared__ __align__(16) unsigned char lds[81920];
    unsigned char* ldsA = lds;
    unsigned char* ldsR = lds + 49152;
    unsigned char* ldsO = lds + 65536;

    int tid = threadIdx.x;
    int wid = tid >> 6, lane = tid & 63, lr = lane & 15, lq = lane >> 4;

    #pragma unroll
    for (int j = 0; j < 6; ++j) {
        int cbase = j * 512 + wid * 64;
        gll16(wc2 + (size_t)(cbase + lane) * 8, ldsA + cbase * 16);
    }
    #pragma unroll
    for (int j = 0; j < 2; ++j) {
        int cbase = j * 512 + wid * 64;
        gll16(wr2 + (size_t)(cbase + lane) * 8, ldsR + cbase * 16);
    }

    int bid = blockIdx.x;
    int wg = (bid & 7) * 64 + (bid >> 3);
    int b = wg >> 6;
    int t0 = ((wg & 63) << 7) + wid * 16;

    const unsigned short* hb = h_in + (size_t)b * Tx * 64;
    short8 bv[3][2];
    #pragma unroll
    for (int tap = 0; tap < 3; ++tap) {
        int toff = (tap - 1) * dil;
        int t = t0 + lr + toff;
        bool v = ((unsigned)t < (unsigned)Tx);
        #pragma unroll
        for (int kc = 0; kc < 2; ++kc) {
            short8 z = {0, 0, 0, 0, 0, 0, 0, 0};
            if (v) z = *(const short8*)(hb + t * 64 + kc * 32 + lq * 8);
            bv[tap][kc] = z;
        }
    }

    f32x4 acc[8];
    #pragma unroll
    for (int mf = 0; mf < 8; ++mf)
        acc[mf] = *(const f32x4*)(gbias + b * 128 + mf * 16 + lq * 4);
    __syncthreads();

    #pragma unroll
    for (int tap = 0; tap < 3; ++tap) {
        #pragma unroll
        for (int kc = 0; kc < 2; ++kc) {
            #pragma unroll
            for (int mf = 0; mf < 8; ++mf) {
                int row = tap * 128 + mf * 16 + lr;
                short8 af = *(const short8*)(ldsA + row * 128 + ((kc * 64 + lq * 16) ^ ((lr & 7) << 4)));
                acc[mf] = __builtin_amdgcn_mfma_f32_16x16x32_bf16(af, bv[tap][kc], acc[mf], 0, 0, 0);
            }
        }
    }

    size_t base = ((size_t)b * Tx + t0 + lr) * 64;
    f32x4 sko[4];
    #pragma unroll
    for (int mf = 0; mf < 4; ++mf)
        sko[mf] = *(const f32x4*)(skips + base + mf * 16 + lq * 4);

    unsigned char* myO = ldsO + wid * 2048;
    #pragma unroll
    for (int mf = 0; mf < 4; ++mf) {
        int p = lr;
        unsigned short ob[4];
        #pragma unroll
        for (int r = 0; r < 4; ++r) {
            float g = acc[mf][r];
            float f = acc[mf + 4][r];
            f = fminf(f, 15.f);
            g = fminf(g, 30.f);
            float ea = __builtin_amdgcn_exp2f(f * 2.8853900817779268f);
            float eb = __builtin_amdgcn_exp2f(g * 1.4426950408889634f);
            float num = (ea - 1.f) * eb;
            float den = (ea + 1.f) * (1.f + eb);
            ob[r] = f2bf(num * __builtin_amdgcn_rcpf(den));
        }
        u32x2 pk;
        pk[0] = (unsigned int)ob[0] | ((unsigned int)ob[1] << 16);
        pk[1] = (unsigned int)ob[2] | ((unsigned int)ob[3] << 16);
        *(u32x2*)(myO + p * 128 + ((mf * 32 + lq * 8) ^ ((p & 7) << 4))) = pk;
    }

    f32x4 racc[4];
    #pragma unroll
    for (int mf = 0; mf < 4; ++mf)
        racc[mf] = *(const f32x4*)(rsb + 64 + mf * 16 + lq * 4) + sko[mf];
    #pragma unroll
    for (int kc = 0; kc < 2; ++kc) {
        int p = lr;
        short8 ov = *(const short8*)(myO + p * 128 + ((kc * 64 + lq * 16) ^ ((p & 7) << 4)));
        #pragma unroll
        for (int mf = 0; mf < 4; ++mf) {
            int row = 64 + mf * 16 + lr;
            short8 af = *(const short8*)(ldsR + row * 128 + ((kc * 64 + lq * 16) ^ ((lr & 7) << 4)));
            racc[mf] = __builtin_amdgcn_mfma_f32_16x16x32_bf16(af, ov, racc[mf], 0, 0, 0);
        }
    }

    #pragma unroll
    for (int mf = 0; mf < 4; ++mf) {
        int p = lr;
        u32x2 pk;
        pk[0] = (unsigned int)f2bf(racc[mf][0]) | ((unsigned int)f2bf(racc[mf][1]) << 16);
        pk[1] = (unsigned int)f2bf(racc[mf][2]) | ((unsigned int)f2bf(racc[mf][3]) << 16);
        *(u32x2*)(myO + p * 128 + ((mf * 32 + lq * 8) ^ ((p & 7) << 4))) = pk;
    }

    f32x4 yacc[4];
    #pragma unroll
    for (int mf = 0; mf < 4; ++mf)
        yacc[mf] = *(const f32x4*)(skb + mf * 16 + lq * 4);
    #pragma unroll
    for (int kc = 0; kc < 2; ++kc) {
        int p = lr;
        short8 Bv = *(const short8*)(myO + p * 128 + ((kc * 64 + lq * 16) ^ ((p & 7) << 4)));
        #pragma unroll
        for (int mf = 0; mf < 4; ++mf) {
            short8 A1 = *(const short8*)(skw + (mf * 16 + lr) * 64 + kc * 32 + lq * 8);
            yacc[mf] = __builtin_amdgcn_mfma_f32_16x16x32_bf16(A1, Bv, yacc[mf], 0, 0, 0);
        }
    }
    #pragma unroll
    for (int mf = 0; mf < 4; ++mf) {
        int p = lr;
        u32x2 pk;
        pk[0] = (unsigned int)f2bf(fmaxf(yacc[mf][0], 0.f)) | ((unsigned int)f2bf(fmaxf(yacc[mf][1], 0.f)) << 16);
        pk[1] = (unsigned int)f2bf(fmaxf(yacc[mf][2], 0.f)) | ((unsigned int)f2bf(fmaxf(yacc[mf][3], 0.f)) << 16);
        *(u32x2*)(myO + p * 128 + ((mf * 32 + lq * 8) ^ ((p & 7) << 4))) = pk;
    }

    f32x4 oacc[5];
    #pragma unroll
    for (int mf = 0; mf < 5; ++mf)
        oacc[mf] = *(const f32x4*)(obias + mf * 16 + lq * 4);
    #pragma unroll
    for (int kc = 0; kc < 2; ++kc) {
        int p = lr;
        short8 B2 = *(const short8*)(myO + p * 128 + ((kc * 64 + lq * 16) ^ ((p & 7) << 4)));
        #pragma unroll
        for (int mf = 0; mf < 5; ++mf) {
            short8 A2 = *(const short8*)(oww + (mf * 16 + lr) * 64 + kc * 32 + lq * 8);
            oacc[mf] = __builtin_amdgcn_mfma_f32_16x16x32_bf16(A2, B2, oacc[mf], 0, 0, 0);
        }
    }
    int t = t0 + lr;
    #pragma unroll
    for (int mf = 0; mf < 5; ++mf) {
        #pragma unroll
        for (int r = 0; r < 4; ++r) {
            int m = mf * 16 + lq * 4 + r;
            y[((size_t)b * NM + m) * Tx + t] = oacc[mf][r];
        }
    }
}

extern "C" void kernel_launch(void* const* d_in, const int* in_sizes, int n_in,
                              void* d_out, int out_size, void* d_ws, size_t ws_size,
                              hipStream_t stream) {
    const float* x       = (const float*)d_in[0];
    const int*   tin     = (const int*)d_in[1];
    const float* c_emb   = (const float*)d_in[2];
    const float* in_w    = (const float*)d_in[3];
    const float* in_b    = (const float*)d_in[4];
    const float* te_w1   = (const float*)d_in[5];
    const float* te_b1   = (const float*)d_in[6];
    const float* te_w2   = (const float*)d_in[7];
    const float* te_b2   = (const float*)d_in[8];
    const float* dconv_w = (const float*)d_in[9];
    const float* dconv_b = (const float*)d_in[10];
    const float* tproj_w = (const float*)d_in[11];
    const float* tproj_b = (const float*)d_in[12];
    const float* cproj_w = (const float*)d_in[13];
    const float* cproj_b = (const float*)d_in[14];
    const float* rs_w    = (const float*)d_in[15];
    const float* rs_b    = (const float*)d_in[16];
    const float* skip_w  = (const float*)d_in[17];
    const float* skip_b  = (const float*)d_in[18];
    const float* out_w   = (const float*)d_in[19];
    const float* out_b   = (const float*)d_in[20];

    char* ws = (char*)d_ws;
    float* te_buf         = (float*)(ws + 0);                 // 4KB
    float* gbias          = (float*)(ws + 4096);              // 120KB -> 126976
    unsigned short* skw16 = (unsigned short*)(ws + 126976);   // 8KB  -> 135168
    unsigned short* oww16 = (unsigned short*)(ws + 135168);   // 10KB -> 145408
    unsigned short* wc2   = (unsigned short*)(ws + 145408);   // 1.40625MB -> 1619968
    unsigned short* wr2   = (unsigned short*)(ws + 1619968);  // 480KB -> 2111488
    unsigned short* h0    = (unsigned short*)(ws + 2111488);  // 8MB -> 10500096
    unsigned short* h1    = (unsigned short*)(ws + 10500096); // 8MB -> 18888704
    float* skips          = (float*)(ws + 18888704);          // 16MB -> 35665920

    setup_kernel<<<325, 512, 0, stream>>>(tin, te_w1, te_b1, te_w2, te_b2, te_buf,
                                          dconv_w, rs_w, skip_w, out_w,
                                          wc2, wr2, skw16, oww16,
                                          x, in_w, in_b, h0);
    gbias_kernel<<<240, 512, 0, stream>>>(te_buf, c_emb, tproj_w, tproj_b,
                                          cproj_w, cproj_b, dconv_b, gbias);

    unsigned short* hin = h0;
    unsigned short* hout = h1;
    for (int i = 0; i < NL - 1; ++i) {
        int dil = 1 << (i % 10);
        layer_kernel<<<512, 512, 0, stream>>>(hin, hout, skips,
                                              wc2 + (size_t)i * 24576,
                                              wr2 + (size_t)i * 8192,
                                              gbias + (size_t)i * 1024,
                                              rs_b + (size_t)i * 128,
                                              dil, i == 0 ? 1 : 0);
        unsigned short* tmp = hin; hin = hout; hout = tmp;
    }
    layer_last_kernel<<<512, 512, 0, stream>>>(hin, skips,
                                               wc2 + (size_t)(NL - 1) * 24576,
                                               wr2 + (size_t)(NL - 1) * 8192,
                                               gbias + (size_t)(NL - 1) * 1024,
                                               rs_b + (size_t)(NL - 1) * 128,
                                               skw16, skip_b, oww16, out_b,
                                               (float*)d_out, 1 << ((NL - 1) % 10));
}